// Round 1
// baseline (42.171 us; speedup 1.0000x reference)
//
#include <hip/hip_runtime.h>

constexpr int NQ = 4;
constexpr int DIM = 16;          // 2^NQ
constexpr int NL = 2;            // layers
constexpr float MARGIN = 0.3f;

// Simulate one 4-qubit circuit entirely in registers.
// ry/rz: 8 angles each, layout [l*NQ + q].
// Qubit q == flat-index bit (NQ-1-q).
__device__ __forceinline__ void simulate(const float ry[NL*NQ], const float rz[NL*NQ],
                                         float sr[DIM], float si[DIM]) {
#pragma unroll
  for (int i = 0; i < DIM; ++i) { sr[i] = 0.0f; si[i] = 0.0f; }
  sr[0] = 1.0f;

#pragma unroll
  for (int l = 0; l < NL; ++l) {
#pragma unroll
    for (int q = 0; q < NQ; ++q) {
      const int bit = 1 << (NQ - 1 - q);
      // RY(theta): [c, -s; s, c] on (a0, a1), real coefficients
      float s, c;
      __sincosf(ry[l*NQ + q] * 0.5f, &s, &c);
#pragma unroll
      for (int i = 0; i < DIM; ++i) {
        if (i & bit) continue;
        const int j = i | bit;
        const float a0r = sr[i], a0i = si[i];
        const float a1r = sr[j], a1i = si[j];
        sr[i] = c*a0r - s*a1r;  si[i] = c*a0i - s*a1i;
        sr[j] = s*a0r + c*a1r;  si[j] = s*a0i + c*a1i;
      }
      // RZ(theta): bit=0 -> e^{-i t/2}, bit=1 -> e^{+i t/2}
      float sz, cz;
      __sincosf(rz[l*NQ + q] * 0.5f, &sz, &cz);
#pragma unroll
      for (int i = 0; i < DIM; ++i) {
        const float pi_ = (i & bit) ? sz : -sz;   // imag part of phase
        const float r = sr[i], im = si[i];
        sr[i] = r*cz - im*pi_;
        si[i] = r*pi_ + im*cz;
      }
    }
    // CNOT ladder: control q, target q+1
#pragma unroll
    for (int q = 0; q < NQ - 1; ++q) {
      const int pc = 1 << (NQ - 1 - q);
      const int pt = 1 << (NQ - 2 - q);
#pragma unroll
      for (int i = 0; i < DIM; ++i) {
        if ((i & pc) && !(i & pt)) {
          const int j = i | pt;
          const float tr = sr[i], ti = si[i];
          sr[i] = sr[j]; si[i] = si[j];
          sr[j] = tr;    si[j] = ti;
        }
      }
    }
  }
}

__device__ __forceinline__ void load8(const float* __restrict__ p, int b, float a[8]) {
  const float4* v = reinterpret_cast<const float4*>(p) + (size_t)b * 2;
  float4 x0 = v[0], x1 = v[1];
  a[0]=x0.x; a[1]=x0.y; a[2]=x0.z; a[3]=x0.w;
  a[4]=x1.x; a[5]=x1.y; a[6]=x1.z; a[7]=x1.w;
}

__global__ __launch_bounds__(256) void triplet_main(
    const float* __restrict__ a_ry, const float* __restrict__ a_rz,
    const float* __restrict__ p_ry, const float* __restrict__ p_rz,
    const float* __restrict__ n_ry, const float* __restrict__ n_rz,
    float* __restrict__ block_sums, int batch) {
  const int b = blockIdx.x * blockDim.x + threadIdx.x;

  float loss = 0.0f;
  if (b < batch) {
    float ry[8], rz[8];
    // anchor
    load8(a_ry, b, ry); load8(a_rz, b, rz);
    float asr[DIM], asi[DIM];
    simulate(ry, rz, asr, asi);

    // positive
    load8(p_ry, b, ry); load8(p_rz, b, rz);
    float xr[DIM], xi[DIM];
    simulate(ry, rz, xr, xi);
    float ovr = 0.f, ovi = 0.f;
#pragma unroll
    for (int i = 0; i < DIM; ++i) {
      ovr += asr[i]*xr[i] + asi[i]*xi[i];
      ovi += asr[i]*xi[i] - asi[i]*xr[i];
    }
    const float fid_pos = ovr*ovr + ovi*ovi;

    // negative (reuse xr/xi)
    load8(n_ry, b, ry); load8(n_rz, b, rz);
    simulate(ry, rz, xr, xi);
    ovr = 0.f; ovi = 0.f;
#pragma unroll
    for (int i = 0; i < DIM; ++i) {
      ovr += asr[i]*xr[i] + asi[i]*xi[i];
      ovi += asr[i]*xi[i] - asi[i]*xr[i];
    }
    const float fid_neg = ovr*ovr + ovi*ovi;

    loss = fmaxf(MARGIN - fid_pos + fid_neg, 0.0f);
  }

  // wave (64) reduce, then LDS across the 4 waves
#pragma unroll
  for (int off = 32; off >= 1; off >>= 1)
    loss += __shfl_down(loss, off, 64);

  __shared__ float wsum[4];
  const int lane = threadIdx.x & 63;
  const int wid  = threadIdx.x >> 6;
  if (lane == 0) wsum[wid] = loss;
  __syncthreads();
  if (threadIdx.x == 0) {
    block_sums[blockIdx.x] = wsum[0] + wsum[1] + wsum[2] + wsum[3];
  }
}

__global__ __launch_bounds__(256) void triplet_reduce(
    const float* __restrict__ block_sums, int nblocks, float* __restrict__ out, float inv_batch) {
  float s = 0.0f;
  for (int i = threadIdx.x; i < nblocks; i += 256) s += block_sums[i];
#pragma unroll
  for (int off = 32; off >= 1; off >>= 1)
    s += __shfl_down(s, off, 64);

  __shared__ float wsum[4];
  const int lane = threadIdx.x & 63;
  const int wid  = threadIdx.x >> 6;
  if (lane == 0) wsum[wid] = s;
  __syncthreads();
  if (threadIdx.x == 0) {
    out[0] = (wsum[0] + wsum[1] + wsum[2] + wsum[3]) * inv_batch;
  }
}

extern "C" void kernel_launch(void* const* d_in, const int* in_sizes, int n_in,
                              void* d_out, int out_size, void* d_ws, size_t ws_size,
                              hipStream_t stream) {
  const float* a_ry = (const float*)d_in[0];
  const float* a_rz = (const float*)d_in[1];
  const float* p_ry = (const float*)d_in[2];
  const float* p_rz = (const float*)d_in[3];
  const float* n_ry = (const float*)d_in[4];
  const float* n_rz = (const float*)d_in[5];
  float* out = (float*)d_out;

  const int batch = in_sizes[0] / (NL * NQ);
  const int nblocks = (batch + 255) / 256;
  float* block_sums = (float*)d_ws;

  triplet_main<<<nblocks, 256, 0, stream>>>(a_ry, a_rz, p_ry, p_rz, n_ry, n_rz,
                                            block_sums, batch);
  triplet_reduce<<<1, 256, 0, stream>>>(block_sums, nblocks, out, 1.0f / (float)batch);
}

// Round 2
// 31.983 us; speedup vs baseline: 1.3185x; 1.3185x over previous
//
#include <hip/hip_runtime.h>

constexpr int NQ = 4;
constexpr int DIM = 16;          // 2^NQ
constexpr int NL = 2;            // layers
constexpr float MARGIN = 0.3f;

// CNOT ladder: CNOT(0,1), CNOT(1,2), CNOT(2,3). Qubit q == flat bit (3-q).
// Pure register permutation -> zero instructions after unrolling.
__device__ __forceinline__ void cnot_ladder(float sr[DIM], float si[DIM]) {
#pragma unroll
  for (int q = 0; q < NQ - 1; ++q) {
    const int pc = 1 << (NQ - 1 - q);
    const int pt = 1 << (NQ - 2 - q);
#pragma unroll
    for (int i = 0; i < DIM; ++i) {
      if ((i & pc) && !(i & pt)) {
        const int j = i | pt;
        const float tr = sr[i], ti = si[i];
        sr[i] = sr[j]; si[i] = si[j];
        sr[j] = tr;    si[j] = ti;
      }
    }
  }
}

// Simulate the 2-layer circuit up to a global phase, skipping the FINAL CNOT
// ladder (it cancels in <psi_a|psi_p> since both circuits end with it).
// Layer 1 on |0...0> is a product state: u_q = (cos(ry/2), sin(ry/2)*e^{i rz})
// (RZ written as diag(1, e^{i phi}) -- global phase dropped).
__device__ __forceinline__ void simulate(const float ry[NL*NQ], const float rz[NL*NQ],
                                         float sr[DIM], float si[DIM]) {
  // --- layer 1: per-qubit 2-vectors ---
  float c0[NQ], pr[NQ], pi_[NQ];
#pragma unroll
  for (int q = 0; q < NQ; ++q) {
    float sy, cy; __sincosf(ry[q] * 0.5f, &sy, &cy);
    float sz, cz; __sincosf(rz[q], &sz, &cz);
    c0[q] = cy;             // amplitude for bit=0 (real)
    pr[q] = sy * cz;        // amplitude for bit=1 (complex)
    pi_[q] = sy * sz;
  }
  // tensor product tree; bit for qubit q is (3-q): amp[i] = prod_q u_q[(i>>(3-q))&1]
  float t2r[4], t2i[4];
  t2r[0] = c0[0]*c0[1];                      t2i[0] = 0.0f;
  t2r[1] = c0[0]*pr[1];                      t2i[1] = c0[0]*pi_[1];
  t2r[2] = pr[0]*c0[1];                      t2i[2] = pi_[0]*c0[1];
  t2r[3] = pr[0]*pr[1] - pi_[0]*pi_[1];      t2i[3] = pr[0]*pi_[1] + pi_[0]*pr[1];
  float t3r[8], t3i[8];
#pragma unroll
  for (int k = 0; k < 4; ++k) {
    t3r[2*k]   = t2r[k]*c0[2];                     t3i[2*k]   = t2i[k]*c0[2];
    t3r[2*k+1] = t2r[k]*pr[2] - t2i[k]*pi_[2];     t3i[2*k+1] = t2r[k]*pi_[2] + t2i[k]*pr[2];
  }
#pragma unroll
  for (int k = 0; k < 8; ++k) {
    sr[2*k]   = t3r[k]*c0[3];                      si[2*k]   = t3i[k]*c0[3];
    sr[2*k+1] = t3r[k]*pr[3] - t3i[k]*pi_[3];      si[2*k+1] = t3r[k]*pi_[3] + t3i[k]*pr[3];
  }

  // --- inter-layer CNOT ladder (free permutation) ---
  cnot_ladder(sr, si);

  // --- layer 2: RY butterflies + RZ(diag(1, e^{i phi})) ---
#pragma unroll
  for (int q = 0; q < NQ; ++q) {
    const int bit = 1 << (NQ - 1 - q);
    float sy, cy; __sincosf(ry[NQ + q] * 0.5f, &sy, &cy);
#pragma unroll
    for (int i = 0; i < DIM; ++i) {
      if (i & bit) continue;
      const int j = i | bit;
      const float a0r = sr[i], a0i = si[i];
      const float a1r = sr[j], a1i = si[j];
      sr[i] = cy*a0r - sy*a1r;  si[i] = cy*a0i - sy*a1i;
      sr[j] = sy*a0r + cy*a1r;  si[j] = sy*a0i + cy*a1i;
    }
    float sz, cz; __sincosf(rz[NQ + q], &sz, &cz);
#pragma unroll
    for (int i = 0; i < DIM; ++i) {
      if (!(i & bit)) continue;
      const float r = sr[i], im = si[i];
      sr[i] = r*cz - im*sz;
      si[i] = r*sz + im*cz;
    }
  }
  // final CNOT ladder deliberately skipped (cancels in the overlap)
}

__device__ __forceinline__ void load8(const float* __restrict__ p, int b, float a[8]) {
  const float4* v = reinterpret_cast<const float4*>(p) + (size_t)b * 2;
  float4 x0 = v[0], x1 = v[1];
  a[0]=x0.x; a[1]=x0.y; a[2]=x0.z; a[3]=x0.w;
  a[4]=x1.x; a[5]=x1.y; a[6]=x1.z; a[7]=x1.w;
}

__global__ __launch_bounds__(256) void triplet_main(
    const float* __restrict__ a_ry, const float* __restrict__ a_rz,
    const float* __restrict__ p_ry, const float* __restrict__ p_rz,
    const float* __restrict__ n_ry, const float* __restrict__ n_rz,
    float* __restrict__ block_sums, int batch) {
  const int b = blockIdx.x * blockDim.x + threadIdx.x;

  float loss = 0.0f;
  if (b < batch) {
    float ry[8], rz[8];
    // anchor
    load8(a_ry, b, ry); load8(a_rz, b, rz);
    float asr[DIM], asi[DIM];
    simulate(ry, rz, asr, asi);

    // positive
    load8(p_ry, b, ry); load8(p_rz, b, rz);
    float xr[DIM], xi[DIM];
    simulate(ry, rz, xr, xi);
    float ovr = 0.f, ovi = 0.f;
#pragma unroll
    for (int i = 0; i < DIM; ++i) {
      ovr += asr[i]*xr[i] + asi[i]*xi[i];
      ovi += asr[i]*xi[i] - asi[i]*xr[i];
    }
    const float fid_pos = ovr*ovr + ovi*ovi;

    // negative (reuse xr/xi)
    load8(n_ry, b, ry); load8(n_rz, b, rz);
    simulate(ry, rz, xr, xi);
    ovr = 0.f; ovi = 0.f;
#pragma unroll
    for (int i = 0; i < DIM; ++i) {
      ovr += asr[i]*xr[i] + asi[i]*xi[i];
      ovi += asr[i]*xi[i] - asi[i]*xr[i];
    }
    const float fid_neg = ovr*ovr + ovi*ovi;

    loss = fmaxf(MARGIN - fid_pos + fid_neg, 0.0f);
  }

  // wave (64) reduce, then LDS across the 4 waves
#pragma unroll
  for (int off = 32; off >= 1; off >>= 1)
    loss += __shfl_down(loss, off, 64);

  __shared__ float wsum[4];
  const int lane = threadIdx.x & 63;
  const int wid  = threadIdx.x >> 6;
  if (lane == 0) wsum[wid] = loss;
  __syncthreads();
  if (threadIdx.x == 0) {
    block_sums[blockIdx.x] = wsum[0] + wsum[1] + wsum[2] + wsum[3];
  }
}

__global__ __launch_bounds__(256) void triplet_reduce(
    const float* __restrict__ block_sums, int nblocks, float* __restrict__ out, float inv_batch) {
  float s = 0.0f;
  for (int i = threadIdx.x; i < nblocks; i += 256) s += block_sums[i];
#pragma unroll
  for (int off = 32; off >= 1; off >>= 1)
    s += __shfl_down(s, off, 64);

  __shared__ float wsum[4];
  const int lane = threadIdx.x & 63;
  const int wid  = threadIdx.x >> 6;
  if (lane == 0) wsum[wid] = s;
  __syncthreads();
  if (threadIdx.x == 0) {
    out[0] = (wsum[0] + wsum[1] + wsum[2] + wsum[3]) * inv_batch;
  }
}

extern "C" void kernel_launch(void* const* d_in, const int* in_sizes, int n_in,
                              void* d_out, int out_size, void* d_ws, size_t ws_size,
                              hipStream_t stream) {
  const float* a_ry = (const float*)d_in[0];
  const float* a_rz = (const float*)d_in[1];
  const float* p_ry = (const float*)d_in[2];
  const float* p_rz = (const float*)d_in[3];
  const float* n_ry = (const float*)d_in[4];
  const float* n_rz = (const float*)d_in[5];
  float* out = (float*)d_out;

  const int batch = in_sizes[0] / (NL * NQ);
  const int nblocks = (batch + 255) / 256;
  float* block_sums = (float*)d_ws;

  triplet_main<<<nblocks, 256, 0, stream>>>(a_ry, a_rz, p_ry, p_rz, n_ry, n_rz,
                                            block_sums, batch);
  triplet_reduce<<<1, 256, 0, stream>>>(block_sums, nblocks, out, 1.0f / (float)batch);
}

// Round 3
// 29.457 us; speedup vs baseline: 1.4316x; 1.0858x over previous
//
#include <hip/hip_runtime.h>

typedef float v2f __attribute__((ext_vector_type(2)));

constexpr int NQ = 4;
constexpr int DIM = 16;          // 2^NQ
constexpr float MARGIN = 0.3f;
constexpr float INV2PI = 0.15915494309189535f;

__device__ __forceinline__ v2f mk2(float x, float y) { v2f r; r.x = x; r.y = y; return r; }

// complex multiply a*b where bs = {-b.y, b.x} is precomputed.
// a.xx*b + a.yy*bs -> 2 packed FMAs (op_sel broadcast/swizzle)
__device__ __forceinline__ v2f cmul_pre(v2f a, v2f b, v2f bs) {
  return a.xx * b + a.yy * bs;
}

__device__ __forceinline__ void sincos_hw(float rev, float& s, float& c) {
  s = __builtin_amdgcn_sinf(rev);   // input in revolutions
  c = __builtin_amdgcn_cosf(rev);
}

// CNOT ladder: CNOT(q,q+1) for q=0..2. Qubit q == flat bit (3-q).
// Pure register permutation after unrolling.
__device__ __forceinline__ void cnot_ladder(v2f s[DIM]) {
#pragma unroll
  for (int q = 0; q < NQ - 1; ++q) {
    const int pc = 1 << (NQ - 1 - q);
    const int pt = 1 << (NQ - 2 - q);
#pragma unroll
    for (int i = 0; i < DIM; ++i) {
      if ((i & pc) && !(i & pt)) {
        const int j = i | pt;
        v2f t = s[i]; s[i] = s[j]; s[j] = t;
      }
    }
  }
}

// 2-layer circuit up to global phase; final CNOT ladder skipped (cancels in
// the overlap since both circuits end with the same ladder).
// Layer 1 on |0000> is a product state: u_q = (cos(ry/2), sin(ry/2) e^{i rz})
// with RZ taken as diag(1, e^{i phi}) (global phase dropped).
__device__ __forceinline__ void simulate(const float ry[8], const float rz[8], v2f s[DIM]) {
  // --- layer 1: per-qubit 2-vectors ---
  float c0[NQ]; v2f p1[NQ], p1s[NQ];
#pragma unroll
  for (int q = 0; q < NQ; ++q) {
    float sy, cy; sincos_hw(ry[q] * (0.5f * INV2PI), sy, cy);
    float sz, cz; sincos_hw(rz[q] * INV2PI, sz, cz);
    c0[q]  = cy;
    p1[q]  = mk2(sy * cz, sy * sz);
    p1s[q] = mk2(-p1[q].y, p1[q].x);
  }
  // tensor-product tree; qubit q is flat bit (3-q)
  v2f t2[4];
  t2[0] = mk2(c0[0] * c0[1], 0.0f);
  t2[1] = c0[0] * p1[1];
  t2[2] = c0[1] * p1[0];
  t2[3] = cmul_pre(p1[0], p1[1], p1s[1]);
  v2f t3[8];
#pragma unroll
  for (int k = 0; k < 4; ++k) {
    t3[2*k]   = t2[k] * c0[2];
    t3[2*k+1] = cmul_pre(t2[k], p1[2], p1s[2]);
  }
#pragma unroll
  for (int k = 0; k < 8; ++k) {
    s[2*k]   = t3[k] * c0[3];
    s[2*k+1] = cmul_pre(t3[k], p1[3], p1s[3]);
  }

  // --- inter-layer CNOT ladder ---
  cnot_ladder(s);

  // --- layer 2: RY butterflies + RZ(diag(1, e^{i phi})) ---
#pragma unroll
  for (int q = 0; q < NQ; ++q) {
    const int bit = 1 << (NQ - 1 - q);
    float sy, cy; sincos_hw(ry[4 + q] * (0.5f * INV2PI), sy, cy);
#pragma unroll
    for (int i = 0; i < DIM; ++i) {
      if (i & bit) continue;
      const int j = i | bit;
      const v2f a0 = s[i], a1 = s[j];
      s[i] = cy * a0 - sy * a1;   // pk_mul + pk_fma (re+im together)
      s[j] = sy * a0 + cy * a1;
    }
    float sz, cz; sincos_hw(rz[4 + q] * INV2PI, sz, cz);
    const v2f ph  = mk2(cz, sz);
    const v2f phs = mk2(-sz, cz);
#pragma unroll
    for (int i = 0; i < DIM; ++i) {
      if (i & bit) s[i] = cmul_pre(s[i], ph, phs);
    }
  }
  // final CNOT ladder deliberately skipped
}

// overlap <a|x>: returns |<a|x>|^2 via two packed accumulator chains
__device__ __forceinline__ float fidelity(const v2f a[DIM], const v2f x[DIM]) {
  v2f ov1 = mk2(0.f, 0.f), ov2 = mk2(0.f, 0.f);
#pragma unroll
  for (int i = 0; i < DIM; ++i) {
    ov1 += a[i].xx * x[i];      // {Σ ar*xr, Σ ar*xi}
    ov2 += a[i].yy * x[i].yx;   // {Σ ai*xi, Σ ai*xr}
  }
  const float ovr = ov1.x + ov2.x;
  const float ovi = ov1.y - ov2.y;
  return ovr * ovr + ovi * ovi;
}

__device__ __forceinline__ void load8(const float* __restrict__ p, int b, float a[8]) {
  const float4* v = reinterpret_cast<const float4*>(p) + (size_t)b * 2;
  float4 x0 = v[0], x1 = v[1];
  a[0]=x0.x; a[1]=x0.y; a[2]=x0.z; a[3]=x0.w;
  a[4]=x1.x; a[5]=x1.y; a[6]=x1.z; a[7]=x1.w;
}

__global__ __launch_bounds__(256) void triplet_main(
    const float* __restrict__ a_ry, const float* __restrict__ a_rz,
    const float* __restrict__ p_ry, const float* __restrict__ p_rz,
    const float* __restrict__ n_ry, const float* __restrict__ n_rz,
    float* __restrict__ block_sums, int batch) {
  const int b = blockIdx.x * blockDim.x + threadIdx.x;

  float loss = 0.0f;
  if (b < batch) {
    float ry[8], rz[8];
    // anchor
    load8(a_ry, b, ry); load8(a_rz, b, rz);
    v2f as[DIM];
    simulate(ry, rz, as);

    // positive
    load8(p_ry, b, ry); load8(p_rz, b, rz);
    v2f xs[DIM];
    simulate(ry, rz, xs);
    const float fid_pos = fidelity(as, xs);

    // negative (reuse xs)
    load8(n_ry, b, ry); load8(n_rz, b, rz);
    simulate(ry, rz, xs);
    const float fid_neg = fidelity(as, xs);

    loss = fmaxf(MARGIN - fid_pos + fid_neg, 0.0f);
  }

  // wave (64) reduce, then LDS across the 4 waves
#pragma unroll
  for (int off = 32; off >= 1; off >>= 1)
    loss += __shfl_down(loss, off, 64);

  __shared__ float wsum[4];
  const int lane = threadIdx.x & 63;
  const int wid  = threadIdx.x >> 6;
  if (lane == 0) wsum[wid] = loss;
  __syncthreads();
  if (threadIdx.x == 0) {
    block_sums[blockIdx.x] = wsum[0] + wsum[1] + wsum[2] + wsum[3];
  }
}

__global__ __launch_bounds__(256) void triplet_reduce(
    const float* __restrict__ block_sums, int nblocks, float* __restrict__ out, float inv_batch) {
  float s = 0.0f;
  for (int i = threadIdx.x; i < nblocks; i += 256) s += block_sums[i];
#pragma unroll
  for (int off = 32; off >= 1; off >>= 1)
    s += __shfl_down(s, off, 64);

  __shared__ float wsum[4];
  const int lane = threadIdx.x & 63;
  const int wid  = threadIdx.x >> 6;
  if (lane == 0) wsum[wid] = s;
  __syncthreads();
  if (threadIdx.x == 0) {
    out[0] = (wsum[0] + wsum[1] + wsum[2] + wsum[3]) * inv_batch;
  }
}

extern "C" void kernel_launch(void* const* d_in, const int* in_sizes, int n_in,
                              void* d_out, int out_size, void* d_ws, size_t ws_size,
                              hipStream_t stream) {
  const float* a_ry = (const float*)d_in[0];
  const float* a_rz = (const float*)d_in[1];
  const float* p_ry = (const float*)d_in[2];
  const float* p_rz = (const float*)d_in[3];
  const float* n_ry = (const float*)d_in[4];
  const float* n_rz = (const float*)d_in[5];
  float* out = (float*)d_out;

  const int batch = in_sizes[0] / 8;       // NL*NQ = 8 angles per element
  const int nblocks = (batch + 255) / 256;
  float* block_sums = (float*)d_ws;

  triplet_main<<<nblocks, 256, 0, stream>>>(a_ry, a_rz, p_ry, p_rz, n_ry, n_rz,
                                            block_sums, batch);
  triplet_reduce<<<1, 256, 0, stream>>>(block_sums, nblocks, out, 1.0f / (float)batch);
}